// Round 15
// baseline (545.575 us; speedup 1.0000x reference)
//
#include <hip/hip_runtime.h>
#include <hip/hip_bf16.h>

#define N_NODES 50000
#define N_EDGES 800000
#define F_IN 9
#define H 128
#define G_GRAPHS 64
#define HH (H * H)
#define MAXT (N_EDGES / 16 + N_NODES)   // 100000 upper bound on tile count

typedef short bf16x8 __attribute__((ext_vector_type(8)));
typedef float f32x4 __attribute__((ext_vector_type(4)));
typedef float f32x2 __attribute__((ext_vector_type(2)));

static __device__ inline short f2b(float f) {
    __hip_bfloat16 h = __float2bfloat16(f);
    return *reinterpret_cast<short*>(&h);
}
// packed unpack: lo exact, hi by raw bits (low-16 garbage ~2^-9 relative, below bf16 rounding)
static __device__ inline f32x2 up2(unsigned u) {
    f32x2 r; r.x = __uint_as_float(u << 16); r.y = __uint_as_float(u); return r;
}
static __device__ inline unsigned encodef(float f) {
    unsigned u = __float_as_uint(f);
    return (u & 0x80000000u) ? ~u : (u | 0x80000000u);
}
static __device__ inline float decodef(unsigned u) {
    return __uint_as_float((u & 0x80000000u) ? (u ^ 0x80000000u) : ~u);
}
// packed RNE f32->bf16 pair [gfx950, no builtin]
static __device__ inline unsigned cvtpk(float lo, float hi) {
    unsigned r;
    asm("v_cvt_pk_bf16_f32 %0, %1, %2" : "=v"(r) : "v"(lo), "v"(hi));
    return r;
}

// ---------- dtype detection (+ zero pooled/counts) ----------
__global__ __launch_bounds__(256) void k_detect(const unsigned* __restrict__ x, int* flag,
                                                float* pooled, float* counts) {
    __shared__ int cnt;
    if (threadIdx.x == 0) cnt = 0;
    __syncthreads();
    unsigned u = x[threadIdx.x];
    int e = (u >> 7) & 0xFF;
    if (e >= 0x70 && e <= 0x83) atomicAdd(&cnt, 1);
    if (threadIdx.x < G_GRAPHS) { pooled[threadIdx.x] = 0.f; counts[threadIdx.x] = 0.f; }
    __syncthreads();
    if (threadIdx.x == 0) *flag = (cnt >= 128) ? 1 : 0;
}

// ---------- batched convert of all float inputs (+ zero cursor) ----------
struct CvtArgs { const void* src[15]; float* dst[15]; };

__global__ __launch_bounds__(256) void k_cvt_all(CvtArgs a, const int* __restrict__ flag,
                                                 int* __restrict__ cursor) {
    const int sz[15] = {450000, 1152, 128, 16384, 128, 32768, 128, 16384, 128,
                        16384, 128, 4096, 32, 32, 1};
    const int cvtTotal = 537873;
    int i = blockIdx.x * 256 + threadIdx.x;
    if (i >= cvtTotal) {
        int c = i - cvtTotal;
        if (c < N_NODES) cursor[c] = 0;
        return;
    }
    int fl = *flag;
    int base = 0;
    #pragma unroll
    for (int s = 0; s < 15; ++s) {
        if (i >= base && i < base + sz[s]) {
            int off = i - base;
            float v = fl ? __bfloat162float(((const __hip_bfloat16*)a.src[s])[off])
                         : ((const float*)a.src[s])[off];
            a.dst[s][off] = v;
        }
        base += sz[s];
    }
}

// ---------- all weight fragment tables in one kernel (42 blocks) ----------
__global__ __launch_bounds__(256) void k_prep_all(const float* __restrict__ We1,
                                                  const float* __restrict__ W2,
                                                  const float* __restrict__ Wf1,
                                                  const float* __restrict__ Wf2,
                                                  const float* __restrict__ We2,
                                                  short* WfU, short* WfV, short* WfW2,
                                                  short* WfF1, short* WfF2, short* We2f) {
    int b = blockIdx.x;
    const float* W; const float* Wm = nullptr; short* out; int NT = 8; int tid;
    if (b < 8)       { W = We1;      Wm = We1 + HH; out = WfU;  tid = b * 256 + threadIdx.x; }
    else if (b < 16) { W = We1 + HH; out = WfV;  tid = (b - 8) * 256 + threadIdx.x; }
    else if (b < 24) { W = W2;       out = WfW2; tid = (b - 16) * 256 + threadIdx.x; }
    else if (b < 32) { W = Wf1;      out = WfF1; tid = (b - 24) * 256 + threadIdx.x; }
    else if (b < 40) { W = We2;      out = We2f; tid = (b - 32) * 256 + threadIdx.x; }
    else             { W = Wf2;      out = WfF2; NT = 2; tid = (b - 40) * 256 + threadIdx.x; }
    int total = 4 * NT * 64;
    if (tid >= total) return;
    int kc = tid / (NT * 64);
    int ct = (tid / 64) % NT;
    int lane = tid & 63;
    int Nc = NT * 16;
    int kb = kc * 32 + (lane >> 4) * 8;
    int col = ct * 16 + (lane & 15);
    #pragma unroll
    for (int j = 0; j < 8; ++j) {
        float w = W[(kb + j) * Nc + col];
        if (Wm) w -= Wm[(kb + j) * Nc + col];
        out[tid * 8 + j] = f2b(w);
    }
}

// ---------- CSR build ----------
__global__ __launch_bounds__(256) void k_hist(const int* __restrict__ dst, int* cnt) {
    int e = blockIdx.x * 256 + threadIdx.x;
    if (e < N_EDGES) atomicAdd(&cnt[dst[e]], 1);
}

// dual exclusive scan (deg, ceil(deg/16)) + dis + per-graph counts
__global__ __launch_bounds__(256) void k_scan1d(const int* __restrict__ deg,
                                                int* __restrict__ outA, int* __restrict__ outB,
                                                int* __restrict__ bsA, int* __restrict__ bsB,
                                                float* __restrict__ dis,
                                                const int* __restrict__ batch,
                                                float* __restrict__ counts) {
    __shared__ int ldsA[256], ldsB[256];
    __shared__ float lc[G_GRAPHS];
    if (threadIdx.x < G_GRAPHS) lc[threadIdx.x] = 0.f;
    int base = blockIdx.x * 2048;
    int t = threadIdx.x;
    int localA[8], localB[8];
    int sA = 0, sB = 0;
    #pragma unroll
    for (int j = 0; j < 8; ++j) {
        int idx = base + t * 8 + j;
        int v = (idx < N_NODES) ? deg[idx] : 0;
        int tc = (v + 15) >> 4;
        localA[j] = sA; sA += v;
        localB[j] = sB; sB += tc;
        if (idx < N_NODES) {
            dis[idx] = rsqrtf((float)v + 1.0f);
            atomicAdd(&lc[batch[idx]], 1.0f);
        }
    }
    ldsA[t] = sA; ldsB[t] = sB;
    __syncthreads();
    if (t == 0) {
        int run = 0;
        for (int i = 0; i < 256; ++i) { int v = ldsA[i]; ldsA[i] = run; run += v; }
        bsA[blockIdx.x] = run;
        run = 0;
        for (int i = 0; i < 256; ++i) { int v = ldsB[i]; ldsB[i] = run; run += v; }
        bsB[blockIdx.x] = run;
    }
    __syncthreads();
    int oA = ldsA[t], oB = ldsB[t];
    #pragma unroll
    for (int j = 0; j < 8; ++j) {
        int idx = base + t * 8 + j;
        if (idx < N_NODES) { outA[idx] = oA + localA[j]; outB[idx] = oB + localB[j]; }
    }
    if (threadIdx.x < G_GRAPHS && lc[threadIdx.x] > 0.f)
        atomicAdd(&counts[threadIdx.x], lc[threadIdx.x]);
}

__global__ void k_scan2d(int* bsA, int* bsB, int nb, int* rowptr, int* tstart, int* ntiles) {
    int run = 0;
    for (int i = 0; i < nb; ++i) { int v = bsA[i]; bsA[i] = run; run += v; }
    rowptr[N_NODES] = N_EDGES;
    run = 0;
    for (int i = 0; i < nb; ++i) { int v = bsB[i]; bsB[i] = run; run += v; }
    tstart[N_NODES] = run;
    *ntiles = run;
}

__global__ __launch_bounds__(256) void k_scan3d(int* rowptr, int* tstart,
                                                const int* __restrict__ bsA,
                                                const int* __restrict__ bsB) {
    int idx = blockIdx.x * 256 + threadIdx.x;
    if (idx < N_NODES) {
        rowptr[idx] += bsA[idx >> 11];
        tstart[idx] += bsB[idx >> 11];
    }
}

// scatter: single packed write per edge. tileSrc slot = src | (dst << 16).
__global__ __launch_bounds__(256) void k_scatter(const int* __restrict__ src, const int* __restrict__ dst,
                                                 const int* __restrict__ tstart,
                                                 int* cursor,
                                                 unsigned* __restrict__ tileSrc) {
    int e = blockIdx.x * 256 + threadIdx.x;
    if (e >= N_EDGES) return;
    int d = dst[e];
    int local = atomicSub(&cursor[d], 1) - 1;
    tileSrc[tstart[d] * 16 + local] = (unsigned)src[e] | ((unsigned)d << 16);
}

// tile pad: duplicate last edge into final tile's tail (packed)
__global__ __launch_bounds__(256) void k_tpad(const int* __restrict__ rowptr,
                                              const int* __restrict__ tstart,
                                              unsigned* __restrict__ tileSrc) {
    int n = blockIdx.x * 256 + threadIdx.x;
    if (n >= N_NODES) return;
    int deg = rowptr[n + 1] - rowptr[n];
    int rem = deg & 15;
    if (deg > 0 && rem) {
        int base = tstart[n] * 16;
        unsigned lastV = tileSrc[base + deg - 1];
        int tb = base + (deg & ~15);
        for (int j = rem; j < 16; ++j) tileSrc[tb + j] = lastV;
    }
}

// ---------- GCN1 GEMM: out = (x[M,9] @ W1[9,128]) * dis[row], bf16 ----------
__global__ __launch_bounds__(256) void k_gemm_f32bf_scale(const float* __restrict__ A,
                                                          const float* __restrict__ W,
                                                          const float* __restrict__ dis,
                                                          short* __restrict__ out, int M) {
    __shared__ float w_lds[F_IN * H];
    for (int i = threadIdx.x; i < F_IN * H; i += 256) w_lds[i] = W[i];
    __syncthreads();
    int row = blockIdx.x * 8 + threadIdx.x / 32;
    int c4 = (threadIdx.x & 31) << 2;
    if (row >= M) return;
    const float* a = A + (size_t)row * F_IN;
    float acc0 = 0.f, acc1 = 0.f, acc2 = 0.f, acc3 = 0.f;
    #pragma unroll
    for (int k = 0; k < F_IN; ++k) {
        float av = a[k];
        float4 w = *reinterpret_cast<const float4*>(&w_lds[k * H + c4]);
        acc0 = fmaf(av, w.x, acc0);
        acc1 = fmaf(av, w.y, acc1);
        acc2 = fmaf(av, w.z, acc2);
        acc3 = fmaf(av, w.w, acc3);
    }
    float dv = dis[row];
    uint2 o = make_uint2(cvtpk(acc0 * dv, acc1 * dv), cvtpk(acc2 * dv, acc3 * dv));
    *reinterpret_cast<uint2*>(&out[(size_t)row * H + c4]) = o;
}

// ---------- dual MFMA GEMM (512 thr): U = A@WU + be1 ; V = A@WV ; zero aggEnc strip ----------
__global__ __launch_bounds__(512) void k_gemm_dual(const short* __restrict__ A,
                                                   const short* __restrict__ WfU,
                                                   const short* __restrict__ WfV,
                                                   const float* __restrict__ be1,
                                                   short* __restrict__ U,
                                                   short* __restrict__ V,
                                                   unsigned* __restrict__ aggEnc, int M) {
    __shared__ short wl[32768];
    for (int i = threadIdx.x * 8; i < 16384; i += 4096) {
        *reinterpret_cast<f32x4*>(&wl[i])         = *reinterpret_cast<const f32x4*>(&WfU[i]);
        *reinterpret_cast<f32x4*>(&wl[16384 + i]) = *reinterpret_cast<const f32x4*>(&WfV[i]);
    }
    {
        int r0 = blockIdx.x * 128;
        uint4* base = reinterpret_cast<uint4*>(aggEnc + (size_t)r0 * H);
        const uint4 z = make_uint4(0, 0, 0, 0);
        #pragma unroll
        for (int i = 0; i < 8; ++i) {
            int idx = threadIdx.x + i * 512;
            int row = r0 + (idx >> 5);
            if (row < M) base[idx] = z;
        }
    }
    __syncthreads();
    int wv = threadIdx.x >> 6, lane = threadIdx.x & 63;
    int er = lane & 15, kg = lane >> 4;
    int row0 = (blockIdx.x * 8 + wv) * 16;
    if (row0 >= M) return;
    bf16x8 af[4];
    #pragma unroll
    for (int kc = 0; kc < 4; ++kc)
        af[kc] = *reinterpret_cast<const bf16x8*>(&A[(size_t)(row0 + er) * H + kc * 32 + kg * 8]);
    const f32x4 vzero = {0.f, 0.f, 0.f, 0.f};
    f32x4 acc[8];
    #pragma unroll
    for (int ct = 0; ct < 8; ++ct) acc[ct] = vzero;
    #pragma unroll
    for (int kc = 0; kc < 4; ++kc)
        #pragma unroll
        for (int ct = 0; ct < 8; ++ct) {
            bf16x8 bf = *reinterpret_cast<const bf16x8*>(&wl[((kc * 8 + ct) * 64 + lane) * 8]);
            acc[ct] = __builtin_amdgcn_mfma_f32_16x16x32_bf16(af[kc], bf, acc[ct], 0, 0, 0);
        }
    #pragma unroll
    for (int ct = 0; ct < 8; ++ct) {
        int col = ct * 16 + er;
        float bv = be1[col];
        #pragma unroll
        for (int r = 0; r < 4; ++r)
            U[(size_t)(row0 + kg * 4 + r) * H + col] = f2b(acc[ct][r] + bv);
    }
    #pragma unroll
    for (int ct = 0; ct < 8; ++ct) acc[ct] = vzero;
    #pragma unroll
    for (int kc = 0; kc < 4; ++kc)
        #pragma unroll
        for (int ct = 0; ct < 8; ++ct) {
            bf16x8 bf = *reinterpret_cast<const bf16x8*>(&wl[16384 + ((kc * 8 + ct) * 64 + lane) * 8]);
            acc[ct] = __builtin_amdgcn_mfma_f32_16x16x32_bf16(af[kc], bf, acc[ct], 0, 0, 0);
        }
    #pragma unroll
    for (int ct = 0; ct < 8; ++ct) {
        int col = ct * 16 + er;
        #pragma unroll
        for (int r = 0; r < 4; ++r)
            V[(size_t)(row0 + kg * 4 + r) * H + col] = f2b(acc[ct][r]);
    }
}

// ---------- MFMA GEMM reading EdgeConv aggregate (512 thr) ----------
__global__ __launch_bounds__(512) void k_gemm_scale_agg(const unsigned* __restrict__ aggEnc,
                                                        const float* __restrict__ be2,
                                                        const short* __restrict__ Wf,
                                                        const float* __restrict__ dis,
                                                        short* __restrict__ out, int M) {
    __shared__ short wl[16384];
    for (int i = threadIdx.x * 8; i < 16384; i += 4096)
        *reinterpret_cast<f32x4*>(&wl[i]) = *reinterpret_cast<const f32x4*>(&Wf[i]);
    __syncthreads();
    int wv = threadIdx.x >> 6, lane = threadIdx.x & 63;
    int er = lane & 15, kg = lane >> 4;
    int row0 = (blockIdx.x * 8 + wv) * 16;
    if (row0 >= M) return;
    bf16x8 af[4];
    #pragma unroll
    for (int kc = 0; kc < 4; ++kc) {
        int basec = kc * 32 + kg * 8;
        const unsigned* ap = &aggEnc[(size_t)(row0 + er) * H + basec];
        uint4 q0 = *reinterpret_cast<const uint4*>(ap);
        uint4 q1 = *reinterpret_cast<const uint4*>(ap + 4);
        float f0 = q0.x ? tanhf(decodef(q0.x) + be2[basec + 0]) : 0.f;
        float f1 = q0.y ? tanhf(decodef(q0.y) + be2[basec + 1]) : 0.f;
        float f2 = q0.z ? tanhf(decodef(q0.z) + be2[basec + 2]) : 0.f;
        float f3 = q0.w ? tanhf(decodef(q0.w) + be2[basec + 3]) : 0.f;
        float f4 = q1.x ? tanhf(decodef(q1.x) + be2[basec + 4]) : 0.f;
        float f5 = q1.y ? tanhf(decodef(q1.y) + be2[basec + 5]) : 0.f;
        float f6 = q1.z ? tanhf(decodef(q1.z) + be2[basec + 6]) : 0.f;
        float f7 = q1.w ? tanhf(decodef(q1.w) + be2[basec + 7]) : 0.f;
        union { unsigned u[4]; bf16x8 v; } Afr;
        Afr.u[0] = cvtpk(f0, f1); Afr.u[1] = cvtpk(f2, f3);
        Afr.u[2] = cvtpk(f4, f5); Afr.u[3] = cvtpk(f6, f7);
        af[kc] = Afr.v;
    }
    const f32x4 vzero = {0.f, 0.f, 0.f, 0.f};
    f32x4 acc[8];
    #pragma unroll
    for (int ct = 0; ct < 8; ++ct) acc[ct] = vzero;
    #pragma unroll
    for (int kc = 0; kc < 4; ++kc)
        #pragma unroll
        for (int ct = 0; ct < 8; ++ct) {
            bf16x8 bf = *reinterpret_cast<const bf16x8*>(&wl[((kc * 8 + ct) * 64 + lane) * 8]);
            acc[ct] = __builtin_amdgcn_mfma_f32_16x16x32_bf16(af[kc], bf, acc[ct], 0, 0, 0);
        }
    float dv[4];
    #pragma unroll
    for (int r = 0; r < 4; ++r) dv[r] = dis[row0 + kg * 4 + r];
    #pragma unroll
    for (int ct = 0; ct < 8; ++ct) {
        int col = ct * 16 + er;
        #pragma unroll
        for (int r = 0; r < 4; ++r)
            out[(size_t)(row0 + kg * 4 + r) * H + col] = f2b(acc[ct][r] * dv[r]);
    }
}

// ---------- GCN fused agg+combine (packed tileSrc as CSR, packed-f32 accumulation) ----------
__global__ __launch_bounds__(256) void k_gcn_fused(const int* __restrict__ rowptr,
                                                   const int* __restrict__ tstart,
                                                   const unsigned* __restrict__ tileSrc,
                                                   const short* __restrict__ hWs,
                                                   const float* __restrict__ dis,
                                                   const float* __restrict__ bias,
                                                   short* __restrict__ out) {
    int wv = threadIdx.x >> 6, lane = threadIdx.x & 63;
    const unsigned* hw = (const unsigned*)hWs;
    const f32x2 z2 = {0.f, 0.f};
    for (int n = blockIdx.x * 4 + wv; n < N_NODES; n += gridDim.x * 4) {
        int deg = rowptr[n + 1] - rowptr[n];
        const unsigned* es = &tileSrc[tstart[n] * 16];
        f32x2 sa = z2, sb = z2, sc = z2, sd = z2;
        int e = 0;
        for (; e + 8 <= deg; e += 8) {
            int s0 = es[e] & 0xFFFF,     s1 = es[e + 1] & 0xFFFF;
            int s2 = es[e + 2] & 0xFFFF, s3 = es[e + 3] & 0xFFFF;
            int s4 = es[e + 4] & 0xFFFF, s5 = es[e + 5] & 0xFFFF;
            int s6 = es[e + 6] & 0xFFFF, s7 = es[e + 7] & 0xFFFF;
            unsigned w0 = hw[(size_t)s0 * 64 + lane];
            unsigned w1 = hw[(size_t)s1 * 64 + lane];
            unsigned w2 = hw[(size_t)s2 * 64 + lane];
            unsigned w3 = hw[(size_t)s3 * 64 + lane];
            unsigned w4 = hw[(size_t)s4 * 64 + lane];
            unsigned w5 = hw[(size_t)s5 * 64 + lane];
            unsigned w6 = hw[(size_t)s6 * 64 + lane];
            unsigned w7 = hw[(size_t)s7 * 64 + lane];
            sa += up2(w0); sb += up2(w1); sc += up2(w2); sd += up2(w3);
            sa += up2(w4); sb += up2(w5); sc += up2(w6); sd += up2(w7);
        }
        for (; e + 4 <= deg; e += 4) {
            int s0 = es[e] & 0xFFFF,     s1 = es[e + 1] & 0xFFFF;
            int s2 = es[e + 2] & 0xFFFF, s3 = es[e + 3] & 0xFFFF;
            unsigned w0 = hw[(size_t)s0 * 64 + lane];
            unsigned w1 = hw[(size_t)s1 * 64 + lane];
            unsigned w2 = hw[(size_t)s2 * 64 + lane];
            unsigned w3 = hw[(size_t)s3 * 64 + lane];
            sa += up2(w0); sb += up2(w1); sc += up2(w2); sd += up2(w3);
        }
        for (; e < deg; ++e) sa += up2(hw[(size_t)(es[e] & 0xFFFF) * 64 + lane]);
        f32x2 s = (sa + sb) + (sc + sd);
        float dn = dis[n];
        f32x2 wn2 = up2(hw[(size_t)n * 64 + lane]);
        float r0 = tanhf(dn * (s.x + wn2.x) + bias[lane * 2]);
        float r1 = tanhf(dn * (s.y + wn2.y) + bias[lane * 2 + 1]);
        *reinterpret_cast<unsigned*>(&out[(size_t)n * H + lane * 2]) = cvtpk(r0, r1);
    }
}

// ---------- EdgeConv: persistent blocks, TWO independent tiles per wave iteration ----------
__global__ __launch_bounds__(512) void k_edge_tile(const unsigned* __restrict__ tileSrc,
                                                   const int* __restrict__ ntilesp,
                                                   const short* __restrict__ U,
                                                   const short* __restrict__ V,
                                                   const short* __restrict__ We2f,
                                                   unsigned* aggEnc) {
    __shared__ short wl[16384];
    for (int i = threadIdx.x * 8; i < 16384; i += 4096)
        *reinterpret_cast<f32x4*>(&wl[i]) = *reinterpret_cast<const f32x4*>(&We2f[i]);
    __syncthreads();
    int nt = *ntilesp;
    int wv = threadIdx.x >> 6, lane = threadIdx.x & 63;
    int er = lane & 15, kg = lane >> 4, kseg = kg * 8;
    const int G = gridDim.x * 8;
    const f32x4 vzero = {0.f, 0.f, 0.f, 0.f};
    const f32x2 z2 = {0.f, 0.f};
    for (int tid = blockIdx.x * 8 + wv; tid < nt; tid += 2 * G) {
        int tid2 = tid + G;
        bool v2 = tid2 < nt;
        int tidB = v2 ? tid2 : tid;
        unsigned pk1 = tileSrc[tid * 16 + er];
        unsigned pk2 = tileSrc[tidB * 16 + er];
        int s1 = pk1 & 0xFFFF, n1 = pk1 >> 16;
        int s2 = pk2 & 0xFFFF, n2 = pk2 >> 16;
        f32x4 acc1[8], acc2[8];
        #pragma unroll
        for (int ct = 0; ct < 8; ++ct) { acc1[ct] = vzero; acc2[ct] = vzero; }
        #pragma unroll
        for (int kc = 0; kc < 4; ++kc) {
            uint4 u1 = *reinterpret_cast<const uint4*>(&U[(size_t)n1 * H + kc * 32 + kseg]);
            uint4 w1 = *reinterpret_cast<const uint4*>(&V[(size_t)s1 * H + kc * 32 + kseg]);
            uint4 u2 = *reinterpret_cast<const uint4*>(&U[(size_t)n2 * H + kc * 32 + kseg]);
            uint4 w2 = *reinterpret_cast<const uint4*>(&V[(size_t)s2 * H + kc * 32 + kseg]);
            union { unsigned u[4]; bf16x8 v; } A1, A2;
            f32x2 t;
            t = __builtin_elementwise_max(up2(u1.x) + up2(w1.x), z2); A1.u[0] = cvtpk(t.x, t.y);
            t = __builtin_elementwise_max(up2(u1.y) + up2(w1.y), z2); A1.u[1] = cvtpk(t.x, t.y);
            t = __builtin_elementwise_max(up2(u1.z) + up2(w1.z), z2); A1.u[2] = cvtpk(t.x, t.y);
            t = __builtin_elementwise_max(up2(u1.w) + up2(w1.w), z2); A1.u[3] = cvtpk(t.x, t.y);
            t = __builtin_elementwise_max(up2(u2.x) + up2(w2.x), z2); A2.u[0] = cvtpk(t.x, t.y);
            t = __builtin_elementwise_max(up2(u2.y) + up2(w2.y), z2); A2.u[1] = cvtpk(t.x, t.y);
            t = __builtin_elementwise_max(up2(u2.z) + up2(w2.z), z2); A2.u[2] = cvtpk(t.x, t.y);
            t = __builtin_elementwise_max(up2(u2.w) + up2(w2.w), z2); A2.u[3] = cvtpk(t.x, t.y);
            #pragma unroll
            for (int ct = 0; ct < 8; ++ct) {
                bf16x8 bf = *reinterpret_cast<const bf16x8*>(&wl[((kc * 8 + ct) * 64 + lane) * 8]);
                acc1[ct] = __builtin_amdgcn_mfma_f32_16x16x32_bf16(A1.v, bf, acc1[ct], 0, 0, 0);
                acc2[ct] = __builtin_amdgcn_mfma_f32_16x16x32_bf16(A2.v, bf, acc2[ct], 0, 0, 0);
            }
        }
        float cm1[8], cm2[8];
        #pragma unroll
        for (int ct = 0; ct < 8; ++ct) {
            float a = fmaxf(fmaxf(fmaxf(acc1[ct][0], acc1[ct][1]), acc1[ct][2]), acc1[ct][3]);
            a = fmaxf(a, __shfl_xor(a, 16));
            a = fmaxf(a, __shfl_xor(a, 32));
            cm1[ct] = a;
            float b = fmaxf(fmaxf(fmaxf(acc2[ct][0], acc2[ct][1]), acc2[ct][2]), acc2[ct][3]);
            b = fmaxf(b, __shfl_xor(b, 16));
            b = fmaxf(b, __shfl_xor(b, 32));
            cm2[ct] = b;
        }
        float vA1, vB1, vA2, vB2;
        if (kg == 0)      { vA1 = cm1[0]; vB1 = cm1[1]; vA2 = cm2[0]; vB2 = cm2[1]; }
        else if (kg == 1) { vA1 = cm1[2]; vB1 = cm1[3]; vA2 = cm2[2]; vB2 = cm2[3]; }
        else if (kg == 2) { vA1 = cm1[4]; vB1 = cm1[5]; vA2 = cm2[4]; vB2 = cm2[5]; }
        else              { vA1 = cm1[6]; vB1 = cm1[7]; vA2 = cm2[6]; vB2 = cm2[7]; }
        int colA = (kg * 2) * 16 + er;
        int colB = (kg * 2 + 1) * 16 + er;
        atomicMax(&aggEnc[(size_t)n1 * H + colA], encodef(vA1));
        atomicMax(&aggEnc[(size_t)n1 * H + colB], encodef(vB1));
        if (v2) {
            atomicMax(&aggEnc[(size_t)n2 * H + colA], encodef(vA2));
            atomicMax(&aggEnc[(size_t)n2 * H + colB], encodef(vB2));
        }
    }
}

// ---------- fused final MLP + pooling, reading EdgeConv aggregate directly ----------
__global__ __launch_bounds__(512) void k_final_mlp_agg(const unsigned* __restrict__ aggEnc,
                                                       const float* __restrict__ be2,
                                                       const short* __restrict__ WfF1,
                                                       const short* __restrict__ WfF2,
                                                       const float* __restrict__ bf1,
                                                       const float* __restrict__ bf2,
                                                       const float* __restrict__ Wf3,
                                                       const float* __restrict__ bf3,
                                                       const int* __restrict__ batch,
                                                       float* pooled, int M) {
    __shared__ short wl1[16384];
    __shared__ short wl2[4096];
    __shared__ short tb[8][2048];
    __shared__ float lp[G_GRAPHS];
    for (int i = threadIdx.x * 8; i < 16384; i += 4096)
        *reinterpret_cast<f32x4*>(&wl1[i]) = *reinterpret_cast<const f32x4*>(&WfF1[i]);
    {
        int i = threadIdx.x * 8;
        if (i < 4096)
            *reinterpret_cast<f32x4*>(&wl2[i]) = *reinterpret_cast<const f32x4*>(&WfF2[i]);
    }
    if (threadIdx.x < G_GRAPHS) lp[threadIdx.x] = 0.f;
    __syncthreads();
    int wv = threadIdx.x >> 6, lane = threadIdx.x & 63;
    int er = lane & 15, kg = lane >> 4;
    int row0 = (blockIdx.x * 8 + wv) * 16;
    bool active = row0 < M;
    const f32x4 vzero = {0.f, 0.f, 0.f, 0.f};
    if (active) {
        bf16x8 af[4];
        #pragma unroll
        for (int kc = 0; kc < 4; ++kc) {
            int basec = kc * 32 + kg * 8;
            const unsigned* ap = &aggEnc[(size_t)(row0 + er) * H + basec];
            uint4 q0 = *reinterpret_cast<const uint4*>(ap);
            uint4 q1 = *reinterpret_cast<const uint4*>(ap + 4);
            float f0 = q0.x ? tanhf(decodef(q0.x) + be2[basec + 0]) : 0.f;
            float f1 = q0.y ? tanhf(decodef(q0.y) + be2[basec + 1]) : 0.f;
            float f2 = q0.z ? tanhf(decodef(q0.z) + be2[basec + 2]) : 0.f;
            float f3 = q0.w ? tanhf(decodef(q0.w) + be2[basec + 3]) : 0.f;
            float f4 = q1.x ? tanhf(decodef(q1.x) + be2[basec + 4]) : 0.f;
            float f5 = q1.y ? tanhf(decodef(q1.y) + be2[basec + 5]) : 0.f;
            float f6 = q1.z ? tanhf(decodef(q1.z) + be2[basec + 6]) : 0.f;
            float f7 = q1.w ? tanhf(decodef(q1.w) + be2[basec + 7]) : 0.f;
            union { unsigned u[4]; bf16x8 v; } A;
            A.u[0] = cvtpk(f0, f1); A.u[1] = cvtpk(f2, f3);
            A.u[2] = cvtpk(f4, f5); A.u[3] = cvtpk(f6, f7);
            af[kc] = A.v;
        }
        f32x4 acc[8];
        #pragma unroll
        for (int ct = 0; ct < 8; ++ct) acc[ct] = vzero;
        #pragma unroll
        for (int kc = 0; kc < 4; ++kc)
            #pragma unroll
            for (int ct = 0; ct < 8; ++ct) {
                bf16x8 bf = *reinterpret_cast<const bf16x8*>(&wl1[((kc * 8 + ct) * 64 + lane) * 8]);
                acc[ct] = __builtin_amdgcn_mfma_f32_16x16x32_bf16(af[kc], bf, acc[ct], 0, 0, 0);
            }
        #pragma unroll
        for (int ct = 0; ct < 8; ++ct) {
            int col = ct * 16 + er;
            float bv = bf1[col];
            #pragma unroll
            for (int r = 0; r < 4; ++r)
                tb[wv][(kg * 4 + r) * 128 + col] = f2b(tanhf(acc[ct][r] + bv));
        }
    }
    __syncthreads();
    if (active) {
        bf16x8 af2[4];
        #pragma unroll
        for (int kc = 0; kc < 4; ++kc)
            af2[kc] = *reinterpret_cast<const bf16x8*>(&tb[wv][er * 128 + kc * 32 + kg * 8]);
        f32x4 a2[2];
        a2[0] = vzero; a2[1] = vzero;
        #pragma unroll
        for (int kc = 0; kc < 4; ++kc)
            #pragma unroll
            for (int ct = 0; ct < 2; ++ct) {
                bf16x8 bf = *reinterpret_cast<const bf16x8*>(&wl2[((kc * 2 + ct) * 64 + lane) * 8]);
                a2[ct] = __builtin_amdgcn_mfma_f32_16x16x32_bf16(af2[kc], bf, a2[ct], 0, 0, 0);
            }
        float w3a = Wf3[er], w3b = Wf3[16 + er];
        float b2a = bf2[er], b2b = bf2[16 + er];
        float bf3v = bf3[0];
        float psum[4];
        #pragma unroll
        for (int r = 0; r < 4; ++r) {
            float f2a = tanhf(a2[0][r] + b2a);
            float f2c = tanhf(a2[1][r] + b2b);
            float p = f2a * w3a + f2c * w3b;
            p += __shfl_xor(p, 1);
            p += __shfl_xor(p, 2);
            p += __shfl_xor(p, 4);
            p += __shfl_xor(p, 8);
            psum[r] = p + bf3v;
        }
        if (er == 0) {
            #pragma unroll
            for (int r = 0; r < 4; ++r) {
                int n = row0 + kg * 4 + r;
                if (n < M) atomicAdd(&lp[batch[n]], psum[r]);
            }
        }
    }
    __syncthreads();
    if (threadIdx.x < G_GRAPHS && lp[threadIdx.x] != 0.f)
        atomicAdd(&pooled[threadIdx.x], lp[threadIdx.x]);
}

__global__ __launch_bounds__(64) void k_final(const float* pooled, const float* counts,
                                              void* out, const int* __restrict__ flag) {
    int g = threadIdx.x;
    if (g < G_GRAPHS) {
        float v = pooled[g] / fmaxf(counts[g], 1.0f);
        float s = 1.0f / (1.0f + expf(-v));
        if (*flag) ((__hip_bfloat16*)out)[g] = __float2bfloat16(s);
        else       ((float*)out)[g] = s;
    }
}

extern "C" void kernel_launch(void* const* d_in, const int* in_sizes, int n_in,
                              void* d_out, int out_size, void* d_ws, size_t ws_size,
                              hipStream_t stream) {
    const int* ei    = (const int*)d_in[1];
    const int* src   = ei;
    const int* dst   = ei + N_EDGES;
    const int* batch = (const int*)d_in[2];

    float* ws = (float*)d_ws;
    size_t off = 0;
    auto alloc = [&](size_t n) { off = (off + 3) & ~(size_t)3; float* p = ws + off; off += n; return p; };

    const size_t NH = (size_t)N_NODES * H;
    short* hb     = (short*)alloc(NH / 2);
    short* Ub     = (short*)alloc(NH / 2);
    short* Vb     = (short*)alloc(NH / 2);
    unsigned* aggEnc = (unsigned*)alloc(NH);
    float* xf     = alloc((size_t)N_NODES * F_IN);
    float* dis    = alloc(N_NODES);
    float* pooled = alloc(G_GRAPHS);
    float* counts = alloc(G_GRAPHS);
    int*   flag   = (int*)alloc(1);
    int*   rowptr = (int*)alloc(N_NODES + 1);
    int*   cursor = (int*)alloc(N_NODES);
    int*   bsums  = (int*)alloc(32);
    int*   bsums2 = (int*)alloc(32);
    int*   tstart = (int*)alloc(N_NODES + 1);
    int*   ntiles = (int*)alloc(1);
    unsigned* tileSrc = (unsigned*)alloc((size_t)MAXT * 16);

    float* W1  = alloc(F_IN * H);
    float* b1  = alloc(H);
    float* W2  = alloc(HH);
    float* b2  = alloc(H);
    float* We1 = alloc(2 * HH);
    float* be1 = alloc(H);
    float* We2 = alloc(HH);
    float* be2 = alloc(H);
    float* Wf1 = alloc(HH);
    float* bf1 = alloc(H);
    float* Wf2 = alloc(H * 32);
    float* bf2 = alloc(32);
    float* Wf3 = alloc(32);
    float* bf3 = alloc(4);
    short* WfU  = (short*)alloc(8192);
    short* WfV  = (short*)alloc(8192);
    short* WfW2 = (short*)alloc(8192);
    short* WfF1 = (short*)alloc(8192);
    short* WfF2 = (short*)alloc(2048);
    short* We2f = (short*)alloc(8192);

    const int eB    = (N_EDGES + 255) / 256;
    const int nB    = (N_NODES + 255) / 256;
    const int scanB = (N_NODES + 2047) / 2048;
    const int mfmaB = (N_NODES / 16 + 7) / 8;      // 391 blocks of 512
    const int gcnB  = (N_NODES + 3) / 4;           // 12500
    const int edgeB = 1024;                        // persistent grid-stride (2 tiles/wave)

    k_detect<<<1, 256, 0, stream>>>((const unsigned*)d_in[0], flag, pooled, counts);

    CvtArgs ca;
    const int srcIdx[15] = {0, 3, 4, 5, 6, 7, 8, 9, 10, 11, 12, 13, 14, 15, 16};
    float* dsts[15] = {xf, W1, b1, W2, b2, We1, be1, We2, be2, Wf1, bf1, Wf2, bf2, Wf3, bf3};
    for (int s = 0; s < 15; ++s) { ca.src[s] = d_in[srcIdx[s]]; ca.dst[s] = dsts[s]; }
    const int cvtTotal = 537873 + N_NODES;
    k_cvt_all<<<(cvtTotal + 255) / 256, 256, 0, stream>>>(ca, flag, cursor);

    k_prep_all<<<42, 256, 0, stream>>>(We1, W2, Wf1, Wf2, We2,
                                       WfU, WfV, WfW2, WfF1, WfF2, We2f);

    // CSR + tile-list build (packed tileSrc doubles as CSR)
    k_hist<<<eB, 256, 0, stream>>>(dst, cursor);
    k_scan1d<<<scanB, 256, 0, stream>>>(cursor, rowptr, tstart, bsums, bsums2,
                                        dis, batch, counts);
    k_scan2d<<<1, 1, 0, stream>>>(bsums, bsums2, scanB, rowptr, tstart, ntiles);
    k_scan3d<<<nB, 256, 0, stream>>>(rowptr, tstart, bsums, bsums2);
    k_scatter<<<eB, 256, 0, stream>>>(src, dst, tstart, cursor, tileSrc);
    k_tpad<<<nB, 256, 0, stream>>>(rowptr, tstart, tileSrc);

    // GCN1
    k_gemm_f32bf_scale<<<(N_NODES + 7) / 8, 256, 0, stream>>>(xf, W1, dis, Ub, N_NODES);
    k_gcn_fused<<<gcnB, 256, 0, stream>>>(rowptr, tstart, tileSrc, Ub, dis, b1, hb);

    for (int iter = 0; iter < 3; ++iter) {
        k_gemm_dual<<<mfmaB, 512, 0, stream>>>(hb, WfU, WfV, be1, Ub, Vb, aggEnc, N_NODES);
        k_edge_tile<<<edgeB, 512, 0, stream>>>(tileSrc, ntiles, Ub, Vb, We2f, aggEnc);
        if (iter < 2) {
            k_gemm_scale_agg<<<mfmaB, 512, 0, stream>>>(aggEnc, be2, WfW2, dis, Ub, N_NODES);
            k_gcn_fused<<<gcnB, 256, 0, stream>>>(rowptr, tstart, tileSrc, Ub, dis, b2, hb);
        }
    }

    k_final_mlp_agg<<<mfmaB, 512, 0, stream>>>(aggEnc, be2, WfF1, WfF2, bf1, bf2, Wf3, bf3,
                                               batch, pooled, N_NODES);
    k_final<<<1, 64, 0, stream>>>(pooled, counts, d_out, flag);
}

// Round 16
// 466.663 us; speedup vs baseline: 1.1691x; 1.1691x over previous
//
#include <hip/hip_runtime.h>
#include <hip/hip_bf16.h>

#define N_NODES 50000
#define N_EDGES 800000
#define F_IN 9
#define H 128
#define G_GRAPHS 64
#define HH (H * H)
#define MAXT (N_EDGES / 16 + N_NODES)   // 100000 upper bound on tile count

typedef short bf16x8 __attribute__((ext_vector_type(8)));
typedef float f32x4 __attribute__((ext_vector_type(4)));
typedef float f32x2 __attribute__((ext_vector_type(2)));

static __device__ inline short f2b(float f) {
    __hip_bfloat16 h = __float2bfloat16(f);
    return *reinterpret_cast<short*>(&h);
}
// packed unpack: lo exact, hi by raw bits (low-16 garbage ~2^-9 relative, below bf16 rounding)
static __device__ inline f32x2 up2(unsigned u) {
    f32x2 r; r.x = __uint_as_float(u << 16); r.y = __uint_as_float(u); return r;
}
static __device__ inline unsigned encodef(float f) {
    unsigned u = __float_as_uint(f);
    return (u & 0x80000000u) ? ~u : (u | 0x80000000u);
}
static __device__ inline float decodef(unsigned u) {
    return __uint_as_float((u & 0x80000000u) ? (u ^ 0x80000000u) : ~u);
}
// packed RNE f32->bf16 pair [gfx950, no builtin]
static __device__ inline unsigned cvtpk(float lo, float hi) {
    unsigned r;
    asm("v_cvt_pk_bf16_f32 %0, %1, %2" : "=v"(r) : "v"(lo), "v"(hi));
    return r;
}

// ---------- dtype detection (+ zero pooled/counts) ----------
__global__ __launch_bounds__(256) void k_detect(const unsigned* __restrict__ x, int* flag,
                                                float* pooled, float* counts) {
    __shared__ int cnt;
    if (threadIdx.x == 0) cnt = 0;
    __syncthreads();
    unsigned u = x[threadIdx.x];
    int e = (u >> 7) & 0xFF;
    if (e >= 0x70 && e <= 0x83) atomicAdd(&cnt, 1);
    if (threadIdx.x < G_GRAPHS) { pooled[threadIdx.x] = 0.f; counts[threadIdx.x] = 0.f; }
    __syncthreads();
    if (threadIdx.x == 0) *flag = (cnt >= 128) ? 1 : 0;
}

// ---------- batched convert of all float inputs (+ zero cursor) ----------
struct CvtArgs { const void* src[15]; float* dst[15]; };

__global__ __launch_bounds__(256) void k_cvt_all(CvtArgs a, const int* __restrict__ flag,
                                                 int* __restrict__ cursor) {
    const int sz[15] = {450000, 1152, 128, 16384, 128, 32768, 128, 16384, 128,
                        16384, 128, 4096, 32, 32, 1};
    const int cvtTotal = 537873;
    int i = blockIdx.x * 256 + threadIdx.x;
    if (i >= cvtTotal) {
        int c = i - cvtTotal;
        if (c < N_NODES) cursor[c] = 0;
        return;
    }
    int fl = *flag;
    int base = 0;
    #pragma unroll
    for (int s = 0; s < 15; ++s) {
        if (i >= base && i < base + sz[s]) {
            int off = i - base;
            float v = fl ? __bfloat162float(((const __hip_bfloat16*)a.src[s])[off])
                         : ((const float*)a.src[s])[off];
            a.dst[s][off] = v;
        }
        base += sz[s];
    }
}

// ---------- all weight fragment tables in one kernel (42 blocks) ----------
__global__ __launch_bounds__(256) void k_prep_all(const float* __restrict__ We1,
                                                  const float* __restrict__ W2,
                                                  const float* __restrict__ Wf1,
                                                  const float* __restrict__ Wf2,
                                                  const float* __restrict__ We2,
                                                  short* WfU, short* WfV, short* WfW2,
                                                  short* WfF1, short* WfF2, short* We2f) {
    int b = blockIdx.x;
    const float* W; const float* Wm = nullptr; short* out; int NT = 8; int tid;
    if (b < 8)       { W = We1;      Wm = We1 + HH; out = WfU;  tid = b * 256 + threadIdx.x; }
    else if (b < 16) { W = We1 + HH; out = WfV;  tid = (b - 8) * 256 + threadIdx.x; }
    else if (b < 24) { W = W2;       out = WfW2; tid = (b - 16) * 256 + threadIdx.x; }
    else if (b < 32) { W = Wf1;      out = WfF1; tid = (b - 24) * 256 + threadIdx.x; }
    else if (b < 40) { W = We2;      out = We2f; tid = (b - 32) * 256 + threadIdx.x; }
    else             { W = Wf2;      out = WfF2; NT = 2; tid = (b - 40) * 256 + threadIdx.x; }
    int total = 4 * NT * 64;
    if (tid >= total) return;
    int kc = tid / (NT * 64);
    int ct = (tid / 64) % NT;
    int lane = tid & 63;
    int Nc = NT * 16;
    int kb = kc * 32 + (lane >> 4) * 8;
    int col = ct * 16 + (lane & 15);
    #pragma unroll
    for (int j = 0; j < 8; ++j) {
        float w = W[(kb + j) * Nc + col];
        if (Wm) w -= Wm[(kb + j) * Nc + col];
        out[tid * 8 + j] = f2b(w);
    }
}

// ---------- CSR build ----------
__global__ __launch_bounds__(256) void k_hist(const int* __restrict__ dst, int* cnt) {
    int e = blockIdx.x * 256 + threadIdx.x;
    if (e < N_EDGES) atomicAdd(&cnt[dst[e]], 1);
}

// dual exclusive scan (deg, ceil(deg/16)) + dis + per-graph counts
__global__ __launch_bounds__(256) void k_scan1d(const int* __restrict__ deg,
                                                int* __restrict__ outA, int* __restrict__ outB,
                                                int* __restrict__ bsA, int* __restrict__ bsB,
                                                float* __restrict__ dis,
                                                const int* __restrict__ batch,
                                                float* __restrict__ counts) {
    __shared__ int ldsA[256], ldsB[256];
    __shared__ float lc[G_GRAPHS];
    if (threadIdx.x < G_GRAPHS) lc[threadIdx.x] = 0.f;
    int base = blockIdx.x * 2048;
    int t = threadIdx.x;
    int localA[8], localB[8];
    int sA = 0, sB = 0;
    #pragma unroll
    for (int j = 0; j < 8; ++j) {
        int idx = base + t * 8 + j;
        int v = (idx < N_NODES) ? deg[idx] : 0;
        int tc = (v + 15) >> 4;
        localA[j] = sA; sA += v;
        localB[j] = sB; sB += tc;
        if (idx < N_NODES) {
            dis[idx] = rsqrtf((float)v + 1.0f);
            atomicAdd(&lc[batch[idx]], 1.0f);
        }
    }
    ldsA[t] = sA; ldsB[t] = sB;
    __syncthreads();
    if (t == 0) {
        int run = 0;
        for (int i = 0; i < 256; ++i) { int v = ldsA[i]; ldsA[i] = run; run += v; }
        bsA[blockIdx.x] = run;
        run = 0;
        for (int i = 0; i < 256; ++i) { int v = ldsB[i]; ldsB[i] = run; run += v; }
        bsB[blockIdx.x] = run;
    }
    __syncthreads();
    int oA = ldsA[t], oB = ldsB[t];
    #pragma unroll
    for (int j = 0; j < 8; ++j) {
        int idx = base + t * 8 + j;
        if (idx < N_NODES) { outA[idx] = oA + localA[j]; outB[idx] = oB + localB[j]; }
    }
    if (threadIdx.x < G_GRAPHS && lc[threadIdx.x] > 0.f)
        atomicAdd(&counts[threadIdx.x], lc[threadIdx.x]);
}

__global__ void k_scan2d(int* bsA, int* bsB, int nb, int* rowptr, int* tstart, int* ntiles) {
    int run = 0;
    for (int i = 0; i < nb; ++i) { int v = bsA[i]; bsA[i] = run; run += v; }
    rowptr[N_NODES] = N_EDGES;
    run = 0;
    for (int i = 0; i < nb; ++i) { int v = bsB[i]; bsB[i] = run; run += v; }
    tstart[N_NODES] = run;
    *ntiles = run;
}

__global__ __launch_bounds__(256) void k_scan3d(int* rowptr, int* tstart,
                                                const int* __restrict__ bsA,
                                                const int* __restrict__ bsB) {
    int idx = blockIdx.x * 256 + threadIdx.x;
    if (idx < N_NODES) {
        rowptr[idx] += bsA[idx >> 11];
        tstart[idx] += bsB[idx >> 11];
    }
}

// scatter: single packed write per edge. tileSrc slot = src | (dst << 16).
__global__ __launch_bounds__(256) void k_scatter(const int* __restrict__ src, const int* __restrict__ dst,
                                                 const int* __restrict__ tstart,
                                                 int* cursor,
                                                 unsigned* __restrict__ tileSrc) {
    int e = blockIdx.x * 256 + threadIdx.x;
    if (e >= N_EDGES) return;
    int d = dst[e];
    int local = atomicSub(&cursor[d], 1) - 1;
    tileSrc[tstart[d] * 16 + local] = (unsigned)src[e] | ((unsigned)d << 16);
}

// tile pad: duplicate last edge into final tile's tail (packed)
__global__ __launch_bounds__(256) void k_tpad(const int* __restrict__ rowptr,
                                              const int* __restrict__ tstart,
                                              unsigned* __restrict__ tileSrc) {
    int n = blockIdx.x * 256 + threadIdx.x;
    if (n >= N_NODES) return;
    int deg = rowptr[n + 1] - rowptr[n];
    int rem = deg & 15;
    if (deg > 0 && rem) {
        int base = tstart[n] * 16;
        unsigned lastV = tileSrc[base + deg - 1];
        int tb = base + (deg & ~15);
        for (int j = rem; j < 16; ++j) tileSrc[tb + j] = lastV;
    }
}

// ---------- GCN1 GEMM: out = (x[M,9] @ W1[9,128]) * dis[row], bf16 ----------
__global__ __launch_bounds__(256) void k_gemm_f32bf_scale(const float* __restrict__ A,
                                                          const float* __restrict__ W,
                                                          const float* __restrict__ dis,
                                                          short* __restrict__ out, int M) {
    __shared__ float w_lds[F_IN * H];
    for (int i = threadIdx.x; i < F_IN * H; i += 256) w_lds[i] = W[i];
    __syncthreads();
    int row = blockIdx.x * 8 + threadIdx.x / 32;
    int c4 = (threadIdx.x & 31) << 2;
    if (row >= M) return;
    const float* a = A + (size_t)row * F_IN;
    float acc0 = 0.f, acc1 = 0.f, acc2 = 0.f, acc3 = 0.f;
    #pragma unroll
    for (int k = 0; k < F_IN; ++k) {
        float av = a[k];
        float4 w = *reinterpret_cast<const float4*>(&w_lds[k * H + c4]);
        acc0 = fmaf(av, w.x, acc0);
        acc1 = fmaf(av, w.y, acc1);
        acc2 = fmaf(av, w.z, acc2);
        acc3 = fmaf(av, w.w, acc3);
    }
    float dv = dis[row];
    uint2 o = make_uint2(cvtpk(acc0 * dv, acc1 * dv), cvtpk(acc2 * dv, acc3 * dv));
    *reinterpret_cast<uint2*>(&out[(size_t)row * H + c4]) = o;
}

// ---------- dual MFMA GEMM (512 thr): U = A@WU + be1 ; V = A@WV ; zero aggEnc strip ----------
__global__ __launch_bounds__(512) void k_gemm_dual(const short* __restrict__ A,
                                                   const short* __restrict__ WfU,
                                                   const short* __restrict__ WfV,
                                                   const float* __restrict__ be1,
                                                   short* __restrict__ U,
                                                   short* __restrict__ V,
                                                   unsigned* __restrict__ aggEnc, int M) {
    __shared__ short wl[32768];
    for (int i = threadIdx.x * 8; i < 16384; i += 4096) {
        *reinterpret_cast<f32x4*>(&wl[i])         = *reinterpret_cast<const f32x4*>(&WfU[i]);
        *reinterpret_cast<f32x4*>(&wl[16384 + i]) = *reinterpret_cast<const f32x4*>(&WfV[i]);
    }
    {
        int r0 = blockIdx.x * 128;
        uint4* base = reinterpret_cast<uint4*>(aggEnc + (size_t)r0 * H);
        const uint4 z = make_uint4(0, 0, 0, 0);
        #pragma unroll
        for (int i = 0; i < 8; ++i) {
            int idx = threadIdx.x + i * 512;
            int row = r0 + (idx >> 5);
            if (row < M) base[idx] = z;
        }
    }
    __syncthreads();
    int wv = threadIdx.x >> 6, lane = threadIdx.x & 63;
    int er = lane & 15, kg = lane >> 4;
    int row0 = (blockIdx.x * 8 + wv) * 16;
    if (row0 >= M) return;
    bf16x8 af[4];
    #pragma unroll
    for (int kc = 0; kc < 4; ++kc)
        af[kc] = *reinterpret_cast<const bf16x8*>(&A[(size_t)(row0 + er) * H + kc * 32 + kg * 8]);
    const f32x4 vzero = {0.f, 0.f, 0.f, 0.f};
    f32x4 acc[8];
    #pragma unroll
    for (int ct = 0; ct < 8; ++ct) acc[ct] = vzero;
    #pragma unroll
    for (int kc = 0; kc < 4; ++kc)
        #pragma unroll
        for (int ct = 0; ct < 8; ++ct) {
            bf16x8 bf = *reinterpret_cast<const bf16x8*>(&wl[((kc * 8 + ct) * 64 + lane) * 8]);
            acc[ct] = __builtin_amdgcn_mfma_f32_16x16x32_bf16(af[kc], bf, acc[ct], 0, 0, 0);
        }
    #pragma unroll
    for (int ct = 0; ct < 8; ++ct) {
        int col = ct * 16 + er;
        float bv = be1[col];
        #pragma unroll
        for (int r = 0; r < 4; ++r)
            U[(size_t)(row0 + kg * 4 + r) * H + col] = f2b(acc[ct][r] + bv);
    }
    #pragma unroll
    for (int ct = 0; ct < 8; ++ct) acc[ct] = vzero;
    #pragma unroll
    for (int kc = 0; kc < 4; ++kc)
        #pragma unroll
        for (int ct = 0; ct < 8; ++ct) {
            bf16x8 bf = *reinterpret_cast<const bf16x8*>(&wl[16384 + ((kc * 8 + ct) * 64 + lane) * 8]);
            acc[ct] = __builtin_amdgcn_mfma_f32_16x16x32_bf16(af[kc], bf, acc[ct], 0, 0, 0);
        }
    #pragma unroll
    for (int ct = 0; ct < 8; ++ct) {
        int col = ct * 16 + er;
        #pragma unroll
        for (int r = 0; r < 4; ++r)
            V[(size_t)(row0 + kg * 4 + r) * H + col] = f2b(acc[ct][r]);
    }
}

// ---------- MFMA GEMM reading EdgeConv aggregate (512 thr) ----------
__global__ __launch_bounds__(512) void k_gemm_scale_agg(const unsigned* __restrict__ aggEnc,
                                                        const float* __restrict__ be2,
                                                        const short* __restrict__ Wf,
                                                        const float* __restrict__ dis,
                                                        short* __restrict__ out, int M) {
    __shared__ short wl[16384];
    for (int i = threadIdx.x * 8; i < 16384; i += 4096)
        *reinterpret_cast<f32x4*>(&wl[i]) = *reinterpret_cast<const f32x4*>(&Wf[i]);
    __syncthreads();
    int wv = threadIdx.x >> 6, lane = threadIdx.x & 63;
    int er = lane & 15, kg = lane >> 4;
    int row0 = (blockIdx.x * 8 + wv) * 16;
    if (row0 >= M) return;
    bf16x8 af[4];
    #pragma unroll
    for (int kc = 0; kc < 4; ++kc) {
        int basec = kc * 32 + kg * 8;
        const unsigned* ap = &aggEnc[(size_t)(row0 + er) * H + basec];
        uint4 q0 = *reinterpret_cast<const uint4*>(ap);
        uint4 q1 = *reinterpret_cast<const uint4*>(ap + 4);
        float f0 = q0.x ? tanhf(decodef(q0.x) + be2[basec + 0]) : 0.f;
        float f1 = q0.y ? tanhf(decodef(q0.y) + be2[basec + 1]) : 0.f;
        float f2 = q0.z ? tanhf(decodef(q0.z) + be2[basec + 2]) : 0.f;
        float f3 = q0.w ? tanhf(decodef(q0.w) + be2[basec + 3]) : 0.f;
        float f4 = q1.x ? tanhf(decodef(q1.x) + be2[basec + 4]) : 0.f;
        float f5 = q1.y ? tanhf(decodef(q1.y) + be2[basec + 5]) : 0.f;
        float f6 = q1.z ? tanhf(decodef(q1.z) + be2[basec + 6]) : 0.f;
        float f7 = q1.w ? tanhf(decodef(q1.w) + be2[basec + 7]) : 0.f;
        union { unsigned u[4]; bf16x8 v; } Afr;
        Afr.u[0] = cvtpk(f0, f1); Afr.u[1] = cvtpk(f2, f3);
        Afr.u[2] = cvtpk(f4, f5); Afr.u[3] = cvtpk(f6, f7);
        af[kc] = Afr.v;
    }
    const f32x4 vzero = {0.f, 0.f, 0.f, 0.f};
    f32x4 acc[8];
    #pragma unroll
    for (int ct = 0; ct < 8; ++ct) acc[ct] = vzero;
    #pragma unroll
    for (int kc = 0; kc < 4; ++kc)
        #pragma unroll
        for (int ct = 0; ct < 8; ++ct) {
            bf16x8 bf = *reinterpret_cast<const bf16x8*>(&wl[((kc * 8 + ct) * 64 + lane) * 8]);
            acc[ct] = __builtin_amdgcn_mfma_f32_16x16x32_bf16(af[kc], bf, acc[ct], 0, 0, 0);
        }
    float dv[4];
    #pragma unroll
    for (int r = 0; r < 4; ++r) dv[r] = dis[row0 + kg * 4 + r];
    #pragma unroll
    for (int ct = 0; ct < 8; ++ct) {
        int col = ct * 16 + er;
        #pragma unroll
        for (int r = 0; r < 4; ++r)
            out[(size_t)(row0 + kg * 4 + r) * H + col] = f2b(acc[ct][r] * dv[r]);
    }
}

// ---------- GCN fused agg+combine (packed tileSrc as CSR, packed-f32 accumulation) ----------
__global__ __launch_bounds__(256) void k_gcn_fused(const int* __restrict__ rowptr,
                                                   const int* __restrict__ tstart,
                                                   const unsigned* __restrict__ tileSrc,
                                                   const short* __restrict__ hWs,
                                                   const float* __restrict__ dis,
                                                   const float* __restrict__ bias,
                                                   short* __restrict__ out) {
    int wv = threadIdx.x >> 6, lane = threadIdx.x & 63;
    const unsigned* hw = (const unsigned*)hWs;
    const f32x2 z2 = {0.f, 0.f};
    for (int n = blockIdx.x * 4 + wv; n < N_NODES; n += gridDim.x * 4) {
        int deg = rowptr[n + 1] - rowptr[n];
        const unsigned* es = &tileSrc[tstart[n] * 16];
        f32x2 sa = z2, sb = z2, sc = z2, sd = z2;
        int e = 0;
        for (; e + 8 <= deg; e += 8) {
            int s0 = es[e] & 0xFFFF,     s1 = es[e + 1] & 0xFFFF;
            int s2 = es[e + 2] & 0xFFFF, s3 = es[e + 3] & 0xFFFF;
            int s4 = es[e + 4] & 0xFFFF, s5 = es[e + 5] & 0xFFFF;
            int s6 = es[e + 6] & 0xFFFF, s7 = es[e + 7] & 0xFFFF;
            unsigned w0 = hw[(size_t)s0 * 64 + lane];
            unsigned w1 = hw[(size_t)s1 * 64 + lane];
            unsigned w2 = hw[(size_t)s2 * 64 + lane];
            unsigned w3 = hw[(size_t)s3 * 64 + lane];
            unsigned w4 = hw[(size_t)s4 * 64 + lane];
            unsigned w5 = hw[(size_t)s5 * 64 + lane];
            unsigned w6 = hw[(size_t)s6 * 64 + lane];
            unsigned w7 = hw[(size_t)s7 * 64 + lane];
            sa += up2(w0); sb += up2(w1); sc += up2(w2); sd += up2(w3);
            sa += up2(w4); sb += up2(w5); sc += up2(w6); sd += up2(w7);
        }
        for (; e + 4 <= deg; e += 4) {
            int s0 = es[e] & 0xFFFF,     s1 = es[e + 1] & 0xFFFF;
            int s2 = es[e + 2] & 0xFFFF, s3 = es[e + 3] & 0xFFFF;
            unsigned w0 = hw[(size_t)s0 * 64 + lane];
            unsigned w1 = hw[(size_t)s1 * 64 + lane];
            unsigned w2 = hw[(size_t)s2 * 64 + lane];
            unsigned w3 = hw[(size_t)s3 * 64 + lane];
            sa += up2(w0); sb += up2(w1); sc += up2(w2); sd += up2(w3);
        }
        for (; e < deg; ++e) sa += up2(hw[(size_t)(es[e] & 0xFFFF) * 64 + lane]);
        f32x2 s = (sa + sb) + (sc + sd);
        float dn = dis[n];
        f32x2 wn2 = up2(hw[(size_t)n * 64 + lane]);
        float r0 = tanhf(dn * (s.x + wn2.x) + bias[lane * 2]);
        float r1 = tanhf(dn * (s.y + wn2.y) + bias[lane * 2 + 1]);
        *reinterpret_cast<unsigned*>(&out[(size_t)n * H + lane * 2]) = cvtpk(r0, r1);
    }
}

// ---------- EdgeConv: persistent blocks, one wave per 16-edge tile, packed tileSrc ----------
__global__ __launch_bounds__(512) void k_edge_tile(const unsigned* __restrict__ tileSrc,
                                                   const int* __restrict__ ntilesp,
                                                   const short* __restrict__ U,
                                                   const short* __restrict__ V,
                                                   const short* __restrict__ We2f,
                                                   unsigned* aggEnc) {
    __shared__ short wl[16384];
    for (int i = threadIdx.x * 8; i < 16384; i += 4096)
        *reinterpret_cast<f32x4*>(&wl[i]) = *reinterpret_cast<const f32x4*>(&We2f[i]);
    __syncthreads();
    int nt = *ntilesp;
    int wv = threadIdx.x >> 6, lane = threadIdx.x & 63;
    int er = lane & 15, kg = lane >> 4, kseg = kg * 8;
    const f32x4 vzero = {0.f, 0.f, 0.f, 0.f};
    const f32x2 z2 = {0.f, 0.f};
    for (int tid = blockIdx.x * 8 + wv; tid < nt; tid += gridDim.x * 8) {
        unsigned pk = tileSrc[tid * 16 + er];
        int s = pk & 0xFFFF;
        int n = pk >> 16;                      // uniform across the wave
        f32x4 acc[8];
        #pragma unroll
        for (int ct = 0; ct < 8; ++ct) acc[ct] = vzero;
        #pragma unroll
        for (int kc = 0; kc < 4; ++kc) {
            uint4 uu4 = *reinterpret_cast<const uint4*>(&U[(size_t)n * H + kc * 32 + kseg]);
            uint4 vv4 = *reinterpret_cast<const uint4*>(&V[(size_t)s * H + kc * 32 + kseg]);
            union { unsigned u[4]; bf16x8 v; } A;
            f32x2 t;
            t = __builtin_elementwise_max(up2(uu4.x) + up2(vv4.x), z2); A.u[0] = cvtpk(t.x, t.y);
            t = __builtin_elementwise_max(up2(uu4.y) + up2(vv4.y), z2); A.u[1] = cvtpk(t.x, t.y);
            t = __builtin_elementwise_max(up2(uu4.z) + up2(vv4.z), z2); A.u[2] = cvtpk(t.x, t.y);
            t = __builtin_elementwise_max(up2(uu4.w) + up2(vv4.w), z2); A.u[3] = cvtpk(t.x, t.y);
            #pragma unroll
            for (int ct = 0; ct < 8; ++ct) {
                bf16x8 bf = *reinterpret_cast<const bf16x8*>(&wl[((kc * 8 + ct) * 64 + lane) * 8]);
                acc[ct] = __builtin_amdgcn_mfma_f32_16x16x32_bf16(A.v, bf, acc[ct], 0, 0, 0);
            }
        }
        float cm[8];
        #pragma unroll
        for (int ct = 0; ct < 8; ++ct) {
            float v = fmaxf(fmaxf(fmaxf(acc[ct][0], acc[ct][1]), acc[ct][2]), acc[ct][3]);
            v = fmaxf(v, __shfl_xor(v, 16));
            v = fmaxf(v, __shfl_xor(v, 32));
            cm[ct] = v;
        }
        float vA, vB;
        if (kg == 0)      { vA = cm[0]; vB = cm[1]; }
        else if (kg == 1) { vA = cm[2]; vB = cm[3]; }
        else if (kg == 2) { vA = cm[4]; vB = cm[5]; }
        else              { vA = cm[6]; vB = cm[7]; }
        int colA = (kg * 2) * 16 + er;
        int colB = (kg * 2 + 1) * 16 + er;
        atomicMax(&aggEnc[(size_t)n * H + colA], encodef(vA));
        atomicMax(&aggEnc[(size_t)n * H + colB], encodef(vB));
    }
}

// ---------- fused final MLP + pooling, reading EdgeConv aggregate directly ----------
__global__ __launch_bounds__(512) void k_final_mlp_agg(const unsigned* __restrict__ aggEnc,
                                                       const float* __restrict__ be2,
                                                       const short* __restrict__ WfF1,
                                                       const short* __restrict__ WfF2,
                                                       const float* __restrict__ bf1,
                                                       const float* __restrict__ bf2,
                                                       const float* __restrict__ Wf3,
                                                       const float* __restrict__ bf3,
                                                       const int* __restrict__ batch,
                                                       float* pooled, int M) {
    __shared__ short wl1[16384];
    __shared__ short wl2[4096];
    __shared__ short tb[8][2048];
    __shared__ float lp[G_GRAPHS];
    for (int i = threadIdx.x * 8; i < 16384; i += 4096)
        *reinterpret_cast<f32x4*>(&wl1[i]) = *reinterpret_cast<const f32x4*>(&WfF1[i]);
    {
        int i = threadIdx.x * 8;
        if (i < 4096)
            *reinterpret_cast<f32x4*>(&wl2[i]) = *reinterpret_cast<const f32x4*>(&WfF2[i]);
    }
    if (threadIdx.x < G_GRAPHS) lp[threadIdx.x] = 0.f;
    __syncthreads();
    int wv = threadIdx.x >> 6, lane = threadIdx.x & 63;
    int er = lane & 15, kg = lane >> 4;
    int row0 = (blockIdx.x * 8 + wv) * 16;
    bool active = row0 < M;
    const f32x4 vzero = {0.f, 0.f, 0.f, 0.f};
    if (active) {
        bf16x8 af[4];
        #pragma unroll
        for (int kc = 0; kc < 4; ++kc) {
            int basec = kc * 32 + kg * 8;
            const unsigned* ap = &aggEnc[(size_t)(row0 + er) * H + basec];
            uint4 q0 = *reinterpret_cast<const uint4*>(ap);
            uint4 q1 = *reinterpret_cast<const uint4*>(ap + 4);
            float f0 = q0.x ? tanhf(decodef(q0.x) + be2[basec + 0]) : 0.f;
            float f1 = q0.y ? tanhf(decodef(q0.y) + be2[basec + 1]) : 0.f;
            float f2 = q0.z ? tanhf(decodef(q0.z) + be2[basec + 2]) : 0.f;
            float f3 = q0.w ? tanhf(decodef(q0.w) + be2[basec + 3]) : 0.f;
            float f4 = q1.x ? tanhf(decodef(q1.x) + be2[basec + 4]) : 0.f;
            float f5 = q1.y ? tanhf(decodef(q1.y) + be2[basec + 5]) : 0.f;
            float f6 = q1.z ? tanhf(decodef(q1.z) + be2[basec + 6]) : 0.f;
            float f7 = q1.w ? tanhf(decodef(q1.w) + be2[basec + 7]) : 0.f;
            union { unsigned u[4]; bf16x8 v; } A;
            A.u[0] = cvtpk(f0, f1); A.u[1] = cvtpk(f2, f3);
            A.u[2] = cvtpk(f4, f5); A.u[3] = cvtpk(f6, f7);
            af[kc] = A.v;
        }
        f32x4 acc[8];
        #pragma unroll
        for (int ct = 0; ct < 8; ++ct) acc[ct] = vzero;
        #pragma unroll
        for (int kc = 0; kc < 4; ++kc)
            #pragma unroll
            for (int ct = 0; ct < 8; ++ct) {
                bf16x8 bf = *reinterpret_cast<const bf16x8*>(&wl1[((kc * 8 + ct) * 64 + lane) * 8]);
                acc[ct] = __builtin_amdgcn_mfma_f32_16x16x32_bf16(af[kc], bf, acc[ct], 0, 0, 0);
            }
        #pragma unroll
        for (int ct = 0; ct < 8; ++ct) {
            int col = ct * 16 + er;
            float bv = bf1[col];
            #pragma unroll
            for (int r = 0; r < 4; ++r)
                tb[wv][(kg * 4 + r) * 128 + col] = f2b(tanhf(acc[ct][r] + bv));
        }
    }
    __syncthreads();
    if (active) {
        bf16x8 af2[4];
        #pragma unroll
        for (int kc = 0; kc < 4; ++kc)
            af2[kc] = *reinterpret_cast<const bf16x8*>(&tb[wv][er * 128 + kc * 32 + kg * 8]);
        f32x4 a2[2];
        a2[0] = vzero; a2[1] = vzero;
        #pragma unroll
        for (int kc = 0; kc < 4; ++kc)
            #pragma unroll
            for (int ct = 0; ct < 2; ++ct) {
                bf16x8 bf = *reinterpret_cast<const bf16x8*>(&wl2[((kc * 2 + ct) * 64 + lane) * 8]);
                a2[ct] = __builtin_amdgcn_mfma_f32_16x16x32_bf16(af2[kc], bf, a2[ct], 0, 0, 0);
            }
        float w3a = Wf3[er], w3b = Wf3[16 + er];
        float b2a = bf2[er], b2b = bf2[16 + er];
        float bf3v = bf3[0];
        float psum[4];
        #pragma unroll
        for (int r = 0; r < 4; ++r) {
            float f2a = tanhf(a2[0][r] + b2a);
            float f2c = tanhf(a2[1][r] + b2b);
            float p = f2a * w3a + f2c * w3b;
            p += __shfl_xor(p, 1);
            p += __shfl_xor(p, 2);
            p += __shfl_xor(p, 4);
            p += __shfl_xor(p, 8);
            psum[r] = p + bf3v;
        }
        if (er == 0) {
            #pragma unroll
            for (int r = 0; r < 4; ++r) {
                int n = row0 + kg * 4 + r;
                if (n < M) atomicAdd(&lp[batch[n]], psum[r]);
            }
        }
    }
    __syncthreads();
    if (threadIdx.x < G_GRAPHS && lp[threadIdx.x] != 0.f)
        atomicAdd(&pooled[threadIdx.x], lp[threadIdx.x]);
}

__global__ __launch_bounds__(64) void k_final(const float* pooled, const float* counts,
                                              void* out, const int* __restrict__ flag) {
    int g = threadIdx.x;
    if (g < G_GRAPHS) {
        float v = pooled[g] / fmaxf(counts[g], 1.0f);
        float s = 1.0f / (1.0f + expf(-v));
        if (*flag) ((__hip_bfloat16*)out)[g] = __float2bfloat16(s);
        else       ((float*)out)[g] = s;
    }
}

extern "C" void kernel_launch(void* const* d_in, const int* in_sizes, int n_in,
                              void* d_out, int out_size, void* d_ws, size_t ws_size,
                              hipStream_t stream) {
    const int* ei    = (const int*)d_in[1];
    const int* src   = ei;
    const int* dst   = ei + N_EDGES;
    const int* batch = (const int*)d_in[2];

    float* ws = (float*)d_ws;
    size_t off = 0;
    auto alloc = [&](size_t n) { off = (off + 3) & ~(size_t)3; float* p = ws + off; off += n; return p; };

    const size_t NH = (size_t)N_NODES * H;
    short* hb     = (short*)alloc(NH / 2);
    short* Ub     = (short*)alloc(NH / 2);
    short* Vb     = (short*)alloc(NH / 2);
    unsigned* aggEnc = (unsigned*)alloc(NH);
    float* xf     = alloc((size_t)N_NODES * F_IN);
    float* dis    = alloc(N_NODES);
    float* pooled = alloc(G_GRAPHS);
    float* counts = alloc(G_GRAPHS);
    int*   flag   = (int*)alloc(1);
    int*   rowptr = (int*)alloc(N_NODES + 1);
    int*   cursor = (int*)alloc(N_NODES);
    int*   bsums  = (int*)alloc(32);
    int*   bsums2 = (int*)alloc(32);
    int*   tstart = (int*)alloc(N_NODES + 1);
    int*   ntiles = (int*)alloc(1);
    unsigned* tileSrc = (unsigned*)alloc((size_t)MAXT * 16);

    float* W1  = alloc(F_IN * H);
    float* b1  = alloc(H);
    float* W2  = alloc(HH);
    float* b2  = alloc(H);
    float* We1 = alloc(2 * HH);
    float* be1 = alloc(H);
    float* We2 = alloc(HH);
    float* be2 = alloc(H);
    float* Wf1 = alloc(HH);
    float* bf1 = alloc(H);
    float* Wf2 = alloc(H * 32);
    float* bf2 = alloc(32);
    float* Wf3 = alloc(32);
    float* bf3 = alloc(4);
    short* WfU  = (short*)alloc(8192);
    short* WfV  = (short*)alloc(8192);
    short* WfW2 = (short*)alloc(8192);
    short* WfF1 = (short*)alloc(8192);
    short* WfF2 = (short*)alloc(2048);
    short* We2f = (short*)alloc(8192);

    const int eB    = (N_EDGES + 255) / 256;
    const int nB    = (N_NODES + 255) / 256;
    const int scanB = (N_NODES + 2047) / 2048;
    const int mfmaB = (N_NODES / 16 + 7) / 8;      // 391 blocks of 512
    const int gcnB  = (N_NODES + 3) / 4;           // 12500
    const int edgeB = 1024;                        // persistent grid-stride

    k_detect<<<1, 256, 0, stream>>>((const unsigned*)d_in[0], flag, pooled, counts);

    CvtArgs ca;
    const int srcIdx[15] = {0, 3, 4, 5, 6, 7, 8, 9, 10, 11, 12, 13, 14, 15, 16};
    float* dsts[15] = {xf, W1, b1, W2, b2, We1, be1, We2, be2, Wf1, bf1, Wf2, bf2, Wf3, bf3};
    for (int s = 0; s < 15; ++s) { ca.src[s] = d_in[srcIdx[s]]; ca.dst[s] = dsts[s]; }
    const int cvtTotal = 537873 + N_NODES;
    k_cvt_all<<<(cvtTotal + 255) / 256, 256, 0, stream>>>(ca, flag, cursor);

    k_prep_all<<<42, 256, 0, stream>>>(We1, W2, Wf1, Wf2, We2,
                                       WfU, WfV, WfW2, WfF1, WfF2, We2f);

    // CSR + tile-list build (packed tileSrc doubles as CSR)
    k_hist<<<eB, 256, 0, stream>>>(dst, cursor);
    k_scan1d<<<scanB, 256, 0, stream>>>(cursor, rowptr, tstart, bsums, bsums2,
                                        dis, batch, counts);
    k_scan2d<<<1, 1, 0, stream>>>(bsums, bsums2, scanB, rowptr, tstart, ntiles);
    k_scan3d<<<nB, 256, 0, stream>>>(rowptr, tstart, bsums, bsums2);
    k_scatter<<<eB, 256, 0, stream>>>(src, dst, tstart, cursor, tileSrc);
    k_tpad<<<nB, 256, 0, stream>>>(rowptr, tstart, tileSrc);

    // GCN1
    k_gemm_f32bf_scale<<<(N_NODES + 7) / 8, 256, 0, stream>>>(xf, W1, dis, Ub, N_NODES);
    k_gcn_fused<<<gcnB, 256, 0, stream>>>(rowptr, tstart, tileSrc, Ub, dis, b1, hb);

    for (int iter = 0; iter < 3; ++iter) {
        k_gemm_dual<<<mfmaB, 512, 0, stream>>>(hb, WfU, WfV, be1, Ub, Vb, aggEnc, N_NODES);
        k_edge_tile<<<edgeB, 512, 0, stream>>>(tileSrc, ntiles, Ub, Vb, We2f, aggEnc);
        if (iter < 2) {
            k_gemm_scale_agg<<<mfmaB, 512, 0, stream>>>(aggEnc, be2, WfW2, dis, Ub, N_NODES);
            k_gcn_fused<<<gcnB, 256, 0, stream>>>(rowptr, tstart, tileSrc, Ub, dis, b2, hb);
        }
    }

    k_final_mlp_agg<<<mfmaB, 512, 0, stream>>>(aggEnc, be2, WfF1, WfF2, bf1, bf2, Wf3, bf3,
                                               batch, pooled, N_NODES);
    k_final<<<1, 64, 0, stream>>>(pooled, counts, d_out, flag);
}